// Round 5
// baseline (78.518 us; speedup 1.0000x reference)
//
#include <hip/hip_runtime.h>
#include <math.h>

#define N_WIRES 13
#define DIM 8192
#define N_LAYERS 3
#define N_OUT 10
#define BATCH 512
#define NTHREADS 512

__device__ __forceinline__ void cmul(float& cr, float& ci,
                                     float xr, float xi, float yr, float yi) {
    cr = xr*yr - xi*yi;
    ci = xr*yi + xi*yr;
}

// Gate on a register bit: pairs (k0, k0|MASK) within the 16 per-thread amps.
#define REG_GATE(MASK, W) do { \
    const float4 uA = uu4[l][W][0]; \
    const float4 uB = uu4[l][W][1]; \
    _Pragma("unroll") \
    for (int k0 = 0; k0 < 16; ++k0) { \
        if (k0 & (MASK)) continue; \
        const int k1 = k0 | (MASK); \
        const float a0r=ar[k0], a0i=ai[k0], a1r=ar[k1], a1i=ai[k1]; \
        ar[k0] = uA.x*a0r - uA.y*a0i + uA.z*a1r - uA.w*a1i; \
        ai[k0] = uA.x*a0i + uA.y*a0r + uA.z*a1i + uA.w*a1r; \
        ar[k1] = uB.x*a0r - uB.y*a0i + uB.z*a1r - uB.w*a1i; \
        ai[k1] = uB.x*a0i + uB.y*a0r + uB.z*a1i + uB.w*a1r; \
    } \
} while (0)

// Gate on a lane bit (x bit == tid bit BITP): partner amps via shfl_xor.
#define SHFL_GATE(MASK, W, BITP) do { \
    const float4 uA = uu4[l][W][0]; \
    const float4 uB = uu4[l][W][1]; \
    const bool hb = ((tid >> (BITP)) & 1) != 0; \
    const float uar = hb ? uB.z : uA.x, uai = hb ? uB.w : uA.y; \
    const float upr = hb ? uB.x : uA.z, upi = hb ? uB.y : uA.w; \
    _Pragma("unroll") \
    for (int k = 0; k < 16; ++k) { \
        const float prr = __shfl_xor(ar[k], (MASK)); \
        const float pii = __shfl_xor(ai[k], (MASK)); \
        const float nr = uar*ar[k] - uai*ai[k] + upr*prr - upi*pii; \
        const float ni = uar*ai[k] + uai*ar[k] + upr*pii + upi*prr; \
        ar[k] = nr; ai[k] = ni; \
    } \
} while (0)

__global__ __launch_bounds__(NTHREADS, 2) void vqc_kernel(
    const float* __restrict__ inputs,
    const float* __restrict__ weights,
    const float* __restrict__ embed,
    float* __restrict__ out)
{
    __shared__ float2 s2[DIM];                       // state, LINEAR addressing
    __shared__ float4 uu4[N_LAYERS][N_WIRES][2];     // Rot matrices
    __shared__ float  co[N_LAYERS][N_WIRES];
    __shared__ float  ga[N_LAYERS][N_WIRES];
    __shared__ float2 Ek[N_LAYERS][16];              // exp(-i(S-2C_k)), k = x bits 12..9 (l=0 pre-scaled)
    __shared__ float2 Eh[N_LAYERS][8];               // exp(+2i*C_h), h = x bits 8..6
    __shared__ float2 El[N_LAYERS][64];              // exp(+2i*C_lo), lo = x bits 5..0
    __shared__ float2 G3[N_LAYERS], G12[N_LAYERS], G6[N_LAYERS];
    __shared__ float  red[NTHREADS / 64][N_OUT];

    const int b   = blockIdx.x;
    const int tid = threadIdx.x;

    // ---- setup stage 1 ----
    if (tid < N_LAYERS * N_WIRES) {
        const int l = tid / N_WIRES;
        const int w = tid - l * N_WIRES;
        const int base = (l * N_WIRES + w) * 3;
        const float om = embed[base + 0];
        const float bi = embed[base + 1];
        const float gm = embed[base + 2];
        co[l][w] = inputs[b * N_WIRES + w] * om + bi;
        ga[l][w] = gm;

        const float phi = weights[base + 0];
        const float th  = weights[base + 1];
        const float omg = weights[base + 2];
        float c, s, ca, sa, cb, sb;
        __sincosf(0.5f * th, &s, &c);
        __sincosf(0.5f * (phi + omg), &sa, &ca);
        __sincosf(0.5f * (phi - omg), &sb, &cb);
        uu4[l][w][0] = make_float4( ca * c, -sa * c, -cb * s, -sb * s);  // U00,U01
        uu4[l][w][1] = make_float4( cb * s, -sb * s,  ca * c,  sa * c);  // U10,U11

        if (w == 3 || w == 6 || w == 12) {
            float s2v, c2v; __sincosf(2.f * gm, &s2v, &c2v);
            if (w == 3)  G3[l]  = make_float2(c2v, s2v);
            if (w == 6)  G6[l]  = make_float2(c2v, s2v);
            if (w == 12) G12[l] = make_float2(c2v, s2v);
        }
    }
    __syncthreads();

    // ---- setup stage 2: phase tables ----
    if (tid < N_LAYERS * 16) {                      // Ek (folds S; l=0 folds nrm)
        const int l = tid >> 4, k = tid & 15;
        float S = 0.f;
        #pragma unroll
        for (int w = 0; w < N_WIRES; ++w) S += co[l][w] + ga[l][w];
        const int b3 = (k >> 3) & 1, b2 = (k >> 2) & 1, b1 = (k >> 1) & 1, b0 = k & 1;
        float v = S;
        if (b3) v -= 2.f * co[l][0];
        if (b2) v -= 2.f * co[l][1];
        if (b1) v -= 2.f * co[l][2];
        if (b0) v -= 2.f * co[l][3];
        if (b3 ^ b2) v -= 2.f * ga[l][0];
        if (b2 ^ b1) v -= 2.f * ga[l][1];
        if (b1 ^ b0) v -= 2.f * ga[l][2];
        float sv, cv; __sincosf(v, &sv, &cv);
        const float sc = (l == 0) ? 0.011048543456039806f : 1.f;   // 8192^-0.5
        Ek[l][k] = make_float2(sc * cv, -sc * sv);
    }
    if (tid >= 64 && tid < 64 + N_LAYERS * 8) {     // Eh
        const int t = tid - 64, l = t >> 3, h = t & 7;
        const int b8 = (h >> 2) & 1, b7 = (h >> 1) & 1, b6 = h & 1;
        float T = 0.f;
        if (b8) T += co[l][4];
        if (b7) T += co[l][5];
        if (b6) T += co[l][6];
        if (b8 ^ b7) T += ga[l][4];
        if (b7 ^ b6) T += ga[l][5];
        float sv, cv; __sincosf(2.f * T, &sv, &cv);
        Eh[l][h] = make_float2(cv, sv);
    }
    if (tid >= 128 && tid < 128 + N_LAYERS * 64) {  // El
        const int t = tid - 128, l = t >> 6, m = t & 63;
        const int b5 = (m >> 5) & 1, b4 = (m >> 4) & 1, b3 = (m >> 3) & 1;
        const int b2 = (m >> 2) & 1, b1 = (m >> 1) & 1, b0 = m & 1;
        float T = 0.f;
        if (b5) T += co[l][7];
        if (b4) T += co[l][8];
        if (b3) T += co[l][9];
        if (b2) T += co[l][10];
        if (b1) T += co[l][11];
        if (b0) T += co[l][12];
        if (b5 ^ b4) T += ga[l][7];
        if (b4 ^ b3) T += ga[l][8];
        if (b3 ^ b2) T += ga[l][9];
        if (b2 ^ b1) T += ga[l][10];
        if (b1 ^ b0) T += ga[l][11];
        float sv, cv; __sincosf(2.f * T, &sv, &cv);
        El[l][m] = make_float2(cv, sv);
    }
    __syncthreads();

    // thread-constant values
    const int lam  = tid & 63;
    const int w3   = tid >> 6;
    const int qidx = (w3 << 10) | lam;              // Q-layout base (k bits 9..6 = 0)
    // gather map g(tid) for the fused CNOT permutation (GF2-linear part from tid)
    const int ht = tid ^ (tid >> 1);
    const int gt = (ht & 0x0FFF) ^ ((tid & 1) * 0x1800);   // bits 11,12 corrections
    const bool t8 = ((tid >> 8) & 1) != 0;
    const bool t0 = (tid & 1) != 0;
    const bool cG6 = (((tid >> 6) ^ (tid >> 5)) & 1) != 0;
    const int hidx = (tid >> 6) & 7;
    const int lidx = tid & 63;

    float ar[16], ai[16];

    #pragma unroll 1
    for (int l = 0; l < N_LAYERS; ++l) {
        // ===== Layout P: x = (k<<9) | tid =====
        // per-thread phase factors R_{b0(k),b3(k)}
        float epr, epi;
        cmul(epr, epi, Eh[l][hidx].x, Eh[l][hidx].y, El[l][lidx].x, El[l][lidx].y);
        if (cG6) { float tr_, ti_; cmul(tr_, ti_, epr, epi, G6[l].x, G6[l].y); epr = tr_; epi = ti_; }
        float eg3r, eg3i; cmul(eg3r, eg3i, epr, epi, G3[l].x, G3[l].y);
        const float P0r = t8 ? eg3r : epr,  P0i = t8 ? eg3i : epi;
        const float P1r = t8 ? epr  : eg3r, P1i = t8 ? epi  : eg3i;
        const float g12r = G12[l].x, g12i = G12[l].y;
        const float Q0r = t0 ? g12r : 1.f, Q0i = t0 ? g12i : 0.f;
        const float Q1r = t0 ? 1.f : g12r, Q1i = t0 ? 0.f : g12i;
        float R00r, R00i, R01r, R01i, R10r, R10i, R11r, R11i;
        cmul(R00r, R00i, P0r, P0i, Q0r, Q0i);
        cmul(R01r, R01i, P0r, P0i, Q1r, Q1i);
        cmul(R10r, R10i, P1r, P1i, Q0r, Q0i);
        cmul(R11r, R11i, P1r, P1i, Q1r, Q1i);

        if (l == 0) {
            #pragma unroll
            for (int k = 0; k < 16; ++k) {
                const float Rr = (k & 1) ? ((k & 8) ? R11r : R10r) : ((k & 8) ? R01r : R00r);
                const float Ri = (k & 1) ? ((k & 8) ? R11i : R10i) : ((k & 8) ? R01i : R00i);
                cmul(ar[k], ai[k], Rr, Ri, Ek[l][k].x, Ek[l][k].y);
            }
        } else {
            // fused CNOT-ring permutation as GATHER: read old[g(x)], x = k<<9|tid.
            // g is GF2-linear: g(x) = A(k) ^ g(tid); A(k) folds at compile time.
            #pragma unroll
            for (int k = 0; k < 16; ++k) {
                const int yk = k << 9;
                const int Ak = ((yk ^ (yk >> 1)) & 0x0FFF) ^ (((yk >> 12) & 1) << 12);
                const float2 v = s2[Ak ^ gt];
                const float Rr = (k & 1) ? ((k & 8) ? R11r : R10r) : ((k & 8) ? R01r : R00r);
                const float Ri = (k & 1) ? ((k & 8) ? R11i : R10i) : ((k & 8) ? R01i : R00i);
                float fr, fi; cmul(fr, fi, Rr, Ri, Ek[l][k].x, Ek[l][k].y);
                ar[k] = v.x * fr - v.y * fi;
                ai[k] = v.x * fi + v.y * fr;
            }
        }

        // wires 0-3 on k bits (ascending masks: incremental dependence on loads)
        REG_GATE(1, 3);
        REG_GATE(2, 2);
        REG_GATE(4, 1);
        REG_GATE(8, 0);
        // wires 7-12 on lane bits (no barrier, no LDS state traffic)
        SHFL_GATE(32, 7, 5);
        SHFL_GATE(16, 8, 4);
        SHFL_GATE(8,  9, 3);
        SHFL_GATE(4, 10, 2);
        SHFL_GATE(2, 11, 1);
        SHFL_GATE(1, 12, 0);

        #pragma unroll
        for (int k = 0; k < 16; ++k)
            s2[(k << 9) | tid] = make_float2(ar[k], ai[k]);
        __syncthreads();

        // ===== Layout Q: x = (w3<<10) | (k<<6) | lam ; wires 4-6 on k bits 2..0 =====
        #pragma unroll
        for (int k = 0; k < 16; ++k) {
            const float2 v = s2[qidx | (k << 6)];
            ar[k] = v.x; ai[k] = v.y;
        }
        REG_GATE(1, 6);
        REG_GATE(2, 5);
        REG_GATE(4, 4);

        if (l < N_LAYERS - 1) {
            // write back to OWN slots (per-thread partition: no intra-pass barrier)
            #pragma unroll
            for (int k = 0; k < 16; ++k)
                s2[qidx | (k << 6)] = make_float2(ar[k], ai[k]);
            __syncthreads();
        }
    }

    // ---- fused readout (Q layout): signs from forward-permuted index y(x) ----
    float acc[N_OUT];
    #pragma unroll
    for (int o = 0; o < N_OUT; ++o) acc[o] = 0.f;

    #pragma unroll
    for (int k = 0; k < 16; ++k) {
        const int x = qidx | (k << 6);
        int t = x ^ (x >> 1); t ^= t >> 2; t ^= t >> 4; t ^= t >> 8;
        const int y = (t & 0x0FFF) | (((t ^ (x >> 12)) & 1) << 12);
        const float p = ar[k] * ar[k] + ai[k] * ai[k];
        #pragma unroll
        for (int o = 0; o < N_OUT; ++o)
            acc[o] += ((y >> (12 - o)) & 1) ? -p : p;
    }

    #pragma unroll
    for (int off = 32; off >= 1; off >>= 1) {
        #pragma unroll
        for (int o = 0; o < N_OUT; ++o) acc[o] += __shfl_down(acc[o], off);
    }
    const int wave = tid >> 6;
    const int lane = tid & 63;
    if (lane == 0) {
        #pragma unroll
        for (int o = 0; o < N_OUT; ++o) red[wave][o] = acc[o];
    }
    __syncthreads();
    if (tid < N_OUT) {
        float s = 0.f;
        #pragma unroll
        for (int w = 0; w < NTHREADS / 64; ++w) s += red[w][tid];
        out[b * N_OUT + tid] = s;
    }
}

extern "C" void kernel_launch(void* const* d_in, const int* in_sizes, int n_in,
                              void* d_out, int out_size, void* d_ws, size_t ws_size,
                              hipStream_t stream) {
    const float* inputs  = (const float*)d_in[0];
    const float* weights = (const float*)d_in[1];
    const float* embed   = (const float*)d_in[2];
    float* out = (float*)d_out;
    vqc_kernel<<<BATCH, NTHREADS, 0, stream>>>(inputs, weights, embed, out);
}

// Round 6
// 52.603 us; speedup vs baseline: 1.4926x; 1.4926x over previous
//
#include <hip/hip_runtime.h>
#include <math.h>

#define N_WIRES 13
#define DIM 8192
#define N_LAYERS 3
#define N_OUT 10
#define BATCH 512
#define NTHREADS 512

typedef float v2f __attribute__((ext_vector_type(2)));

// ---- packed complex arithmetic via VOP3P (v_pk_*_f32) ----
// d = u (*) a   [complex mul]: d = (ur*ar - ui*ai, ur*ai + ui*ar)
#define CMUL_PK(d, u, a) do { \
    asm("v_pk_mul_f32 %0, %1, %2 op_sel:[0,0] op_sel_hi:[0,1]" \
        : "=v"(d) : "v"(u), "v"(a)); \
    asm("v_pk_fma_f32 %0, %1, %2, %0 op_sel:[1,1,0] op_sel_hi:[1,0,1] neg_lo:[0,1,0]" \
        : "+v"(d) : "v"(u), "v"(a)); \
} while (0)

// d += u (*) a  [complex fma]
#define CFMA_PK(d, u, a) do { \
    asm("v_pk_fma_f32 %0, %1, %2, %0 op_sel:[0,0,0] op_sel_hi:[0,1,1]" \
        : "+v"(d) : "v"(u), "v"(a)); \
    asm("v_pk_fma_f32 %0, %1, %2, %0 op_sel:[1,1,0] op_sel_hi:[1,0,1] neg_lo:[0,1,0]" \
        : "+v"(d) : "v"(u), "v"(a)); \
} while (0)

__device__ __forceinline__ void bfly(v2f& a0, v2f& a1,
                                     v2f u00, v2f u01, v2f u10, v2f u11) {
    v2f n0, n1;
    CMUL_PK(n0, u00, a0); CFMA_PK(n0, u01, a1);
    CMUL_PK(n1, u10, a0); CFMA_PK(n1, u11, a1);
    a0 = n0; a1 = n1;
}

// Gate on a register bit: pairs (k0, k0|MASK) within the 16 per-thread amps.
#define REG_GATE(MASK, W) do { \
    const float4 uA = uu4[l][W][0]; \
    const float4 uB = uu4[l][W][1]; \
    const v2f u00 = {uA.x, uA.y}, u01 = {uA.z, uA.w}; \
    const v2f u10 = {uB.x, uB.y}, u11 = {uB.z, uB.w}; \
    _Pragma("unroll") \
    for (int k0 = 0; k0 < 16; ++k0) { \
        if (k0 & (MASK)) continue; \
        bfly(a[k0], a[k0 | (MASK)], u00, u01, u10, u11); \
    } \
} while (0)

// Gate on lane bit 0 (x bit 0): partner via ds_swizzle xor-1 (0x041F).
#define SWZ1_GATE(W) do { \
    const float4 uA = uu4[l][W][0]; \
    const float4 uB = uu4[l][W][1]; \
    const bool hb = (tid & 1) != 0; \
    const v2f ua = hb ? (v2f){uB.z, uB.w} : (v2f){uA.x, uA.y}; \
    const v2f up = hb ? (v2f){uB.x, uB.y} : (v2f){uA.z, uA.w}; \
    _Pragma("unroll") \
    for (int k = 0; k < 16; ++k) { \
        v2f p; \
        p.x = __int_as_float(__builtin_amdgcn_ds_swizzle(__float_as_int(a[k].x), 0x041F)); \
        p.y = __int_as_float(__builtin_amdgcn_ds_swizzle(__float_as_int(a[k].y), 0x041F)); \
        v2f n; CMUL_PK(n, ua, a[k]); CFMA_PK(n, up, p); \
        a[k] = n; \
    } \
} while (0)

__global__ __launch_bounds__(NTHREADS, 2) void vqc_kernel(
    const float* __restrict__ inputs,
    const float* __restrict__ weights,
    const float* __restrict__ embed,
    float* __restrict__ out)
{
    __shared__ v2f  s2[DIM];                        // state, XOR-swizzled addressing
    __shared__ float4 uu4[N_LAYERS][N_WIRES][2];    // Rot matrices
    __shared__ float  co[N_LAYERS][N_WIRES];
    __shared__ float  ga[N_LAYERS][N_WIRES];
    __shared__ v2f  Ek[N_LAYERS][16];               // exp(-i(S-2C_k)), k = x bits 12..9 (l=0 pre-scaled)
    __shared__ v2f  Eh[N_LAYERS][8];                // exp(+2i*C_h), h = x bits 8..6
    __shared__ v2f  El[N_LAYERS][64];               // exp(+2i*C_lo), lo = x bits 5..0
    __shared__ v2f  G3[N_LAYERS], G12[N_LAYERS], G6[N_LAYERS];
    __shared__ float red[NTHREADS / 64][N_OUT];

    const int b   = blockIdx.x;
    const int tid = threadIdx.x;

    // ---- setup stage 1: co/ga + U matrices + boundary gamma factors ----
    if (tid < N_LAYERS * N_WIRES) {
        const int l = tid / N_WIRES;
        const int w = tid - l * N_WIRES;
        const int base = (l * N_WIRES + w) * 3;
        const float om = embed[base + 0];
        const float bi = embed[base + 1];
        const float gm = embed[base + 2];
        co[l][w] = inputs[b * N_WIRES + w] * om + bi;
        ga[l][w] = gm;

        const float phi = weights[base + 0];
        const float th  = weights[base + 1];
        const float omg = weights[base + 2];
        float c, s, ca, sa, cb, sb;
        __sincosf(0.5f * th, &s, &c);
        __sincosf(0.5f * (phi + omg), &sa, &ca);
        __sincosf(0.5f * (phi - omg), &sb, &cb);
        uu4[l][w][0] = make_float4( ca * c, -sa * c, -cb * s, -sb * s);  // U00,U01
        uu4[l][w][1] = make_float4( cb * s, -sb * s,  ca * c,  sa * c);  // U10,U11

        if (w == 3 || w == 6 || w == 12) {
            float s2v, c2v; __sincosf(2.f * gm, &s2v, &c2v);
            if (w == 3)  G3[l]  = (v2f){c2v, s2v};
            if (w == 6)  G6[l]  = (v2f){c2v, s2v};
            if (w == 12) G12[l] = (v2f){c2v, s2v};
        }
    }
    __syncthreads();

    // ---- setup stage 2: phase tables ----
    if (tid < N_LAYERS * 16) {                      // Ek (folds S; l=0 folds nrm)
        const int l = tid >> 4, k = tid & 15;
        float S = 0.f;
        #pragma unroll
        for (int w = 0; w < N_WIRES; ++w) S += co[l][w] + ga[l][w];
        const int b3 = (k >> 3) & 1, b2 = (k >> 2) & 1, b1 = (k >> 1) & 1, b0 = k & 1;
        float v = S;
        if (b3) v -= 2.f * co[l][0];
        if (b2) v -= 2.f * co[l][1];
        if (b1) v -= 2.f * co[l][2];
        if (b0) v -= 2.f * co[l][3];
        if (b3 ^ b2) v -= 2.f * ga[l][0];
        if (b2 ^ b1) v -= 2.f * ga[l][1];
        if (b1 ^ b0) v -= 2.f * ga[l][2];
        float sv, cv; __sincosf(v, &sv, &cv);
        const float sc = (l == 0) ? 0.011048543456039806f : 1.f;   // 8192^-0.5
        Ek[l][k] = (v2f){sc * cv, -sc * sv};
    }
    if (tid >= 64 && tid < 64 + N_LAYERS * 8) {     // Eh
        const int t = tid - 64, l = t >> 3, h = t & 7;
        const int b8 = (h >> 2) & 1, b7 = (h >> 1) & 1, b6 = h & 1;
        float T = 0.f;
        if (b8) T += co[l][4];
        if (b7) T += co[l][5];
        if (b6) T += co[l][6];
        if (b8 ^ b7) T += ga[l][4];
        if (b7 ^ b6) T += ga[l][5];
        float sv, cv; __sincosf(2.f * T, &sv, &cv);
        Eh[l][h] = (v2f){cv, sv};
    }
    if (tid >= 128 && tid < 128 + N_LAYERS * 64) {  // El
        const int t = tid - 128, l = t >> 6, m = t & 63;
        const int b5 = (m >> 5) & 1, b4 = (m >> 4) & 1, b3 = (m >> 3) & 1;
        const int b2 = (m >> 2) & 1, b1 = (m >> 1) & 1, b0 = m & 1;
        float T = 0.f;
        if (b5) T += co[l][7];
        if (b4) T += co[l][8];
        if (b3) T += co[l][9];
        if (b2) T += co[l][10];
        if (b1) T += co[l][11];
        if (b0) T += co[l][12];
        if (b5 ^ b4) T += ga[l][7];
        if (b4 ^ b3) T += ga[l][8];
        if (b3 ^ b2) T += ga[l][9];
        if (b2 ^ b1) T += ga[l][10];
        if (b1 ^ b0) T += ga[l][11];
        float sv, cv; __sincosf(2.f * T, &sv, &cv);
        El[l][m] = (v2f){cv, sv};
    }
    __syncthreads();

    // thread-constant addressing (state address = x ^ ((x>>5)&0xE), folded)
    const int tidA   = tid ^ ((tid >> 5) & 0xE);                       // pass A
    const int baseB  = ((tid >> 5) << 9) | (tid & 31);                 // pass B (^ k-const)
    const int xbaseC = ((tid >> 1) << 5) | (tid & 1);                  // pass C true x
    const int baseC  = xbaseC ^ ((tid >> 1) & 0xE);                    // pass C address
    const bool t8 = ((tid >> 8) & 1) != 0;
    const bool t0 = (tid & 1) != 0;
    const bool cG6 = (((tid >> 6) ^ (tid >> 5)) & 1) != 0;
    const int hidx = (tid >> 6) & 7;
    const int lidx = tid & 63;

    v2f a[16];

    #pragma unroll 1
    for (int l = 0; l < N_LAYERS; ++l) {
        // ===== Pass A: x = tid | (k<<9); phase + wires 0-3 =====
        v2f ep; CMUL_PK(ep, Eh[l][hidx], El[l][lidx]);
        { v2f t6; CMUL_PK(t6, ep, G6[l]); ep = cG6 ? t6 : ep; }
        v2f eg3; CMUL_PK(eg3, ep, G3[l]);
        const v2f P0 = t8 ? eg3 : ep,  P1 = t8 ? ep : eg3;
        const v2f one = {1.f, 0.f};
        const v2f Q0 = t0 ? G12[l] : one, Q1 = t0 ? one : G12[l];
        v2f R00, R01, R10, R11;
        CMUL_PK(R00, P0, Q0);
        CMUL_PK(R01, P0, Q1);
        CMUL_PK(R10, P1, Q0);
        CMUL_PK(R11, P1, Q1);

        if (l == 0) {
            #pragma unroll
            for (int k = 0; k < 16; ++k) {
                const v2f Rk = (k & 1) ? ((k & 8) ? R11 : R10) : ((k & 8) ? R01 : R00);
                CMUL_PK(a[k], Rk, Ek[l][k]);
            }
        } else {
            #pragma unroll
            for (int k = 0; k < 16; ++k) {
                const v2f Rk = (k & 1) ? ((k & 8) ? R11 : R10) : ((k & 8) ? R01 : R00);
                v2f f; CMUL_PK(f, Rk, Ek[l][k]);
                const v2f v = s2[tidA | (k << 9)];
                CMUL_PK(a[k], v, f);
            }
        }

        REG_GATE(8, 0);   // wire 0 <-> x bit 12 (k bit 3)
        REG_GATE(4, 1);
        REG_GATE(2, 2);
        REG_GATE(1, 3);

        #pragma unroll
        for (int k = 0; k < 16; ++k)
            s2[tidA | (k << 9)] = a[k];
        __syncthreads();

        // ===== Pass B: x = (tid>>5)<<9 | k<<5 | (tid&31); wires 4-7 =====
        #pragma unroll
        for (int k = 0; k < 16; ++k)
            a[k] = s2[baseB ^ ((k << 5) | (k & 0xE))];
        REG_GATE(8, 4);
        REG_GATE(4, 5);
        REG_GATE(2, 6);
        REG_GATE(1, 7);
        #pragma unroll
        for (int k = 0; k < 16; ++k)
            s2[baseB ^ ((k << 5) | (k & 0xE))] = a[k];
        __syncthreads();

        // ===== Pass C: x = (tid>>1)<<5 | k<<1 | (tid&1); wires 8-11 + 12 =====
        #pragma unroll
        for (int k = 0; k < 16; ++k)
            a[k] = s2[baseC ^ (k << 1)];
        if (l < N_LAYERS - 1) __syncthreads();   // all loads done before scatter

        REG_GATE(8, 8);    // wire 8  <-> x bit 4 (k bit 3)
        REG_GATE(4, 9);
        REG_GATE(2, 10);
        REG_GATE(1, 11);
        SWZ1_GATE(12);     // wire 12 <-> x bit 0 (lane bit 0)

        if (l < N_LAYERS - 1) {
            // fused CNOT-ring permutation: scatter amp(x) to y = suffix-XOR(x)
            #pragma unroll
            for (int k = 0; k < 16; ++k) {
                const int x = xbaseC | (k << 1);
                int t = x ^ (x >> 1); t ^= t >> 2; t ^= t >> 4; t ^= t >> 8;
                const int y = (t & 0x0FFF) | (((t ^ (x >> 12)) & 1) << 12);
                s2[y ^ ((y >> 5) & 0xE)] = a[k];
            }
            __syncthreads();
        }
    }

    // ---- fused readout: signs from final (permuted) index y ----
    float acc[N_OUT];
    #pragma unroll
    for (int o = 0; o < N_OUT; ++o) acc[o] = 0.f;

    #pragma unroll
    for (int k = 0; k < 16; ++k) {
        const int x = xbaseC | (k << 1);
        int t = x ^ (x >> 1); t ^= t >> 2; t ^= t >> 4; t ^= t >> 8;
        const int y = (t & 0x0FFF) | (((t ^ (x >> 12)) & 1) << 12);
        const float p = a[k].x * a[k].x + a[k].y * a[k].y;
        #pragma unroll
        for (int o = 0; o < N_OUT; ++o)
            acc[o] += ((y >> (12 - o)) & 1) ? -p : p;
    }

    #pragma unroll
    for (int off = 32; off >= 1; off >>= 1) {
        #pragma unroll
        for (int o = 0; o < N_OUT; ++o) acc[o] += __shfl_down(acc[o], off);
    }
    const int wave = tid >> 6;
    const int lane = tid & 63;
    if (lane == 0) {
        #pragma unroll
        for (int o = 0; o < N_OUT; ++o) red[wave][o] = acc[o];
    }
    __syncthreads();
    if (tid < N_OUT) {
        float s = 0.f;
        #pragma unroll
        for (int w = 0; w < NTHREADS / 64; ++w) s += red[w][tid];
        out[b * N_OUT + tid] = s;
    }
}

extern "C" void kernel_launch(void* const* d_in, const int* in_sizes, int n_in,
                              void* d_out, int out_size, void* d_ws, size_t ws_size,
                              hipStream_t stream) {
    const float* inputs  = (const float*)d_in[0];
    const float* weights = (const float*)d_in[1];
    const float* embed   = (const float*)d_in[2];
    float* out = (float*)d_out;
    vqc_kernel<<<BATCH, NTHREADS, 0, stream>>>(inputs, weights, embed, out);
}

// Round 7
// 47.487 us; speedup vs baseline: 1.6535x; 1.1077x over previous
//
#include <hip/hip_runtime.h>
#include <math.h>

#define N_WIRES 13
#define DIM 8192
#define N_LAYERS 3
#define N_OUT 10
#define BATCH 512
#define NTHREADS 1024
#define NAMPS 8
#define NWAVES (NTHREADS / 64)

typedef float v2f __attribute__((ext_vector_type(2)));

// ---- packed complex arithmetic via VOP3P (v_pk_*_f32) ----
// d = u (*) a   [complex mul]
#define CMUL_PK(d, u, a) do { \
    asm("v_pk_mul_f32 %0, %1, %2 op_sel:[0,0] op_sel_hi:[0,1]" \
        : "=v"(d) : "v"(u), "v"(a)); \
    asm("v_pk_fma_f32 %0, %1, %2, %0 op_sel:[1,1,0] op_sel_hi:[1,0,1] neg_lo:[0,1,0]" \
        : "+v"(d) : "v"(u), "v"(a)); \
} while (0)

// d += u (*) a  [complex fma]
#define CFMA_PK(d, u, a) do { \
    asm("v_pk_fma_f32 %0, %1, %2, %0 op_sel:[0,0,0] op_sel_hi:[0,1,1]" \
        : "+v"(d) : "v"(u), "v"(a)); \
    asm("v_pk_fma_f32 %0, %1, %2, %0 op_sel:[1,1,0] op_sel_hi:[1,0,1] neg_lo:[0,1,0]" \
        : "+v"(d) : "v"(u), "v"(a)); \
} while (0)

__device__ __forceinline__ void bfly(v2f& a0, v2f& a1,
                                     v2f u00, v2f u01, v2f u10, v2f u11) {
    v2f n0, n1;
    CMUL_PK(n0, u00, a0); CFMA_PK(n0, u01, a1);
    CMUL_PK(n1, u10, a0); CFMA_PK(n1, u11, a1);
    a0 = n0; a1 = n1;
}

// Gate on a register bit: pairs (k0, k0|MASK) within the 8 per-thread amps.
#define REG_GATE(MASK, W) do { \
    const float4 uA = uu4[l][W][0]; \
    const float4 uB = uu4[l][W][1]; \
    const v2f u00 = {uA.x, uA.y}, u01 = {uA.z, uA.w}; \
    const v2f u10 = {uB.x, uB.y}, u11 = {uB.z, uB.w}; \
    _Pragma("unroll") \
    for (int k0 = 0; k0 < NAMPS; ++k0) { \
        if (k0 & (MASK)) continue; \
        bfly(a[k0], a[k0 | (MASK)], u00, u01, u10, u11); \
    } \
} while (0)

// Gate on lane bit 0 (x bit 0): partner via ds_swizzle xor-1 (0x041F).
#define SWZ1_GATE(W) do { \
    const float4 uA = uu4[l][W][0]; \
    const float4 uB = uu4[l][W][1]; \
    const bool hb = (tid & 1) != 0; \
    const v2f ua = hb ? (v2f){uB.z, uB.w} : (v2f){uA.x, uA.y}; \
    const v2f up = hb ? (v2f){uB.x, uB.y} : (v2f){uA.z, uA.w}; \
    _Pragma("unroll") \
    for (int k = 0; k < NAMPS; ++k) { \
        v2f p; \
        p.x = __int_as_float(__builtin_amdgcn_ds_swizzle(__float_as_int(a[k].x), 0x041F)); \
        p.y = __int_as_float(__builtin_amdgcn_ds_swizzle(__float_as_int(a[k].y), 0x041F)); \
        v2f n; CMUL_PK(n, ua, a[k]); CFMA_PK(n, up, p); \
        a[k] = n; \
    } \
} while (0)

__global__ __launch_bounds__(NTHREADS, 8) void vqc_kernel(
    const float* __restrict__ inputs,
    const float* __restrict__ weights,
    const float* __restrict__ embed,
    float* __restrict__ out)
{
    __shared__ v2f  s2[DIM];                        // state, addresses via m(x)=x^(((x>>5)&7)<<1)
    __shared__ float4 uu4[N_LAYERS][N_WIRES][2];    // Rot matrices
    __shared__ float  co[N_LAYERS][N_WIRES];
    __shared__ float  ga[N_LAYERS][N_WIRES];
    __shared__ v2f  Ek[N_LAYERS][8];                // exp(-i(S-2C_k)), k = x bits 12..10 (l=0 pre-scaled)
    __shared__ v2f  Eh[N_LAYERS][16];               // exp(+2i*C_h), h = x bits 9..6
    __shared__ v2f  El[N_LAYERS][64];               // exp(+2i*C_lo), lo = x bits 5..0
    __shared__ v2f  G2[N_LAYERS], G6b[N_LAYERS], G12[N_LAYERS];
    __shared__ float red[NWAVES][N_OUT];

    const int b   = blockIdx.x;
    const int tid = threadIdx.x;

    // ---- setup stage 1: co/ga + U matrices + boundary gamma factors ----
    if (tid < N_LAYERS * N_WIRES) {
        const int l = tid / N_WIRES;
        const int w = tid - l * N_WIRES;
        const int base = (l * N_WIRES + w) * 3;
        const float om = embed[base + 0];
        const float bi = embed[base + 1];
        const float gm = embed[base + 2];
        co[l][w] = inputs[b * N_WIRES + w] * om + bi;
        ga[l][w] = gm;

        const float phi = weights[base + 0];
        const float th  = weights[base + 1];
        const float omg = weights[base + 2];
        float c, s, ca, sa, cb, sb;
        __sincosf(0.5f * th, &s, &c);
        __sincosf(0.5f * (phi + omg), &sa, &ca);
        __sincosf(0.5f * (phi - omg), &sb, &cb);
        uu4[l][w][0] = make_float4( ca * c, -sa * c, -cb * s, -sb * s);  // U00,U01
        uu4[l][w][1] = make_float4( cb * s, -sb * s,  ca * c,  sa * c);  // U10,U11

        if (w == 2 || w == 6 || w == 12) {
            float s2v, c2v; __sincosf(2.f * gm, &s2v, &c2v);
            if (w == 2)  G2[l]  = (v2f){c2v, s2v};   // boundary x10^x9
            if (w == 6)  G6b[l] = (v2f){c2v, s2v};   // boundary x6^x5
            if (w == 12) G12[l] = (v2f){c2v, s2v};   // wrap x0^x12
        }
    }
    __syncthreads();

    // ---- setup stage 2: phase tables ----
    if (tid < N_LAYERS * 8) {                       // Ek: k = x12..10 (wires 0-2), folds S + norm
        const int l = tid >> 3, k = tid & 7;
        float S = 0.f;
        #pragma unroll
        for (int w = 0; w < N_WIRES; ++w) S += co[l][w] + ga[l][w];
        const int b2 = (k >> 2) & 1, b1 = (k >> 1) & 1, b0 = k & 1;
        float v = S;
        if (b2) v -= 2.f * co[l][0];
        if (b1) v -= 2.f * co[l][1];
        if (b0) v -= 2.f * co[l][2];
        if (b2 ^ b1) v -= 2.f * ga[l][0];
        if (b1 ^ b0) v -= 2.f * ga[l][1];
        float sv, cv; __sincosf(v, &sv, &cv);
        const float sc = (l == 0) ? 0.011048543456039806f : 1.f;   // 8192^-0.5
        Ek[l][k] = (v2f){sc * cv, -sc * sv};
    }
    if (tid >= 64 && tid < 64 + N_LAYERS * 16) {    // Eh: h = x9..6 (wires 3-6)
        const int t = tid - 64, l = t >> 4, h = t & 15;
        const int h3 = (h >> 3) & 1, h2 = (h >> 2) & 1, h1 = (h >> 1) & 1, h0 = h & 1;
        float T = 0.f;
        if (h3) T += co[l][3];
        if (h2) T += co[l][4];
        if (h1) T += co[l][5];
        if (h0) T += co[l][6];
        if (h3 ^ h2) T += ga[l][3];
        if (h2 ^ h1) T += ga[l][4];
        if (h1 ^ h0) T += ga[l][5];
        float sv, cv; __sincosf(2.f * T, &sv, &cv);
        Eh[l][h] = (v2f){cv, sv};
    }
    if (tid >= 128 && tid < 128 + N_LAYERS * 64) {  // El: m = x5..0 (wires 7-12)
        const int t = tid - 128, l = t >> 6, m = t & 63;
        const int b5 = (m >> 5) & 1, b4 = (m >> 4) & 1, b3 = (m >> 3) & 1;
        const int b2 = (m >> 2) & 1, b1 = (m >> 1) & 1, b0 = m & 1;
        float T = 0.f;
        if (b5) T += co[l][7];
        if (b4) T += co[l][8];
        if (b3) T += co[l][9];
        if (b2) T += co[l][10];
        if (b1) T += co[l][11];
        if (b0) T += co[l][12];
        if (b5 ^ b4) T += ga[l][7];
        if (b4 ^ b3) T += ga[l][8];
        if (b3 ^ b2) T += ga[l][9];
        if (b2 ^ b1) T += ga[l][10];
        if (b1 ^ b0) T += ga[l][11];
        float sv, cv; __sincosf(2.f * T, &sv, &cv);
        El[l][m] = (v2f){cv, sv};
    }
    __syncthreads();

    // thread-constant addressing; m(x) = x ^ (((x>>5)&7)<<1), folded per pass
    const int tA = tid ^ (((tid >> 5) & 7) << 1);                         // A: addr = (k<<10)|tA
    const int bB = (((tid >> 7) << 10) | (tid & 127))
                 ^ ((((tid >> 6) & 1) << 2) | (((tid >> 5) & 1) << 1));   // B: ^ (k<<7) ^ ((k&1)<<3)
    const int bC = (((tid >> 4) << 7) | (tid & 15))
                 ^ (((tid >> 4) & 1) << 3);                               // C: ^ (k<<4) ^ (k&6)
    const int bD = (((tid >> 1) << 4) | (tid & 1))
                 ^ (((tid >> 2) & 7) << 1);                               // D: ^ (k<<1)
    const int xD = ((tid >> 1) << 4) | (tid & 1);                         // D: true x base
    const bool t9 = ((tid >> 9) & 1) != 0;
    const bool t0 = (tid & 1) != 0;
    const bool c6 = (((tid >> 6) ^ (tid >> 5)) & 1) != 0;
    const int hidx = (tid >> 6) & 15;
    const int lidx = tid & 63;

    v2f a[NAMPS];

    #pragma unroll 1
    for (int l = 0; l < N_LAYERS; ++l) {
        // ===== Pass A: x = (k<<10)|tid; phase + wires 0-2 =====
        v2f ep; CMUL_PK(ep, Eh[l][hidx], El[l][lidx]);
        { v2f tb; CMUL_PK(tb, ep, G6b[l]); ep = c6 ? tb : ep; }
        v2f eg2; CMUL_PK(eg2, ep, G2[l]);
        const v2f P0 = t9 ? eg2 : ep,  P1 = t9 ? ep : eg2;     // by k bit0 (x10) vs t9
        const v2f one = {1.f, 0.f};
        const v2f Q0 = t0 ? G12[l] : one, Q1 = t0 ? one : G12[l]; // by k bit2 (x12) vs t0
        v2f R00, R01, R10, R11;   // R[b0][b2]
        CMUL_PK(R00, P0, Q0);
        CMUL_PK(R01, P0, Q1);
        CMUL_PK(R10, P1, Q0);
        CMUL_PK(R11, P1, Q1);

        if (l == 0) {
            #pragma unroll
            for (int k = 0; k < NAMPS; ++k) {
                const v2f Rk = (k & 1) ? ((k & 4) ? R11 : R10) : ((k & 4) ? R01 : R00);
                CMUL_PK(a[k], Rk, Ek[l][k]);
            }
        } else {
            #pragma unroll
            for (int k = 0; k < NAMPS; ++k) {
                const v2f Rk = (k & 1) ? ((k & 4) ? R11 : R10) : ((k & 4) ? R01 : R00);
                v2f f; CMUL_PK(f, Rk, Ek[l][k]);
                const v2f v = s2[(k << 10) | tA];
                CMUL_PK(a[k], v, f);
            }
        }

        REG_GATE(4, 0);   // wire 0 <-> x12 <-> k bit 2
        REG_GATE(2, 1);
        REG_GATE(1, 2);
        #pragma unroll
        for (int k = 0; k < NAMPS; ++k)
            s2[(k << 10) | tA] = a[k];
        __syncthreads();

        // ===== Pass B: k = x9..7; wires 3-5 =====
        #pragma unroll
        for (int k = 0; k < NAMPS; ++k)
            a[k] = s2[bB ^ (k << 7) ^ ((k & 1) << 3)];
        REG_GATE(4, 3);
        REG_GATE(2, 4);
        REG_GATE(1, 5);
        #pragma unroll
        for (int k = 0; k < NAMPS; ++k)
            s2[bB ^ (k << 7) ^ ((k & 1) << 3)] = a[k];
        __syncthreads();

        // ===== Pass C: k = x6..4; wires 6-8 =====
        #pragma unroll
        for (int k = 0; k < NAMPS; ++k)
            a[k] = s2[bC ^ (k << 4) ^ (k & 6)];
        REG_GATE(4, 6);
        REG_GATE(2, 7);
        REG_GATE(1, 8);
        #pragma unroll
        for (int k = 0; k < NAMPS; ++k)
            s2[bC ^ (k << 4) ^ (k & 6)] = a[k];
        __syncthreads();

        // ===== Pass D: k = x3..1; wires 9-11 + wire 12 (lane bit 0) =====
        #pragma unroll
        for (int k = 0; k < NAMPS; ++k)
            a[k] = s2[bD ^ (k << 1)];
        if (l < N_LAYERS - 1) __syncthreads();   // all loads done before scatter

        REG_GATE(4, 9);
        REG_GATE(2, 10);
        REG_GATE(1, 11);
        SWZ1_GATE(12);

        if (l < N_LAYERS - 1) {
            // fused CNOT-ring permutation: scatter amp(x) to y = suffix-XOR(x)
            #pragma unroll
            for (int k = 0; k < NAMPS; ++k) {
                const int x = xD | (k << 1);
                int t = x ^ (x >> 1); t ^= t >> 2; t ^= t >> 4; t ^= t >> 8;
                const int y = (t & 0x0FFF) | (((t ^ (x >> 12)) & 1) << 12);
                s2[y ^ (((y >> 5) & 7) << 1)] = a[k];
            }
            __syncthreads();
        }
    }

    // ---- fused readout: signs from final (permuted) index y ----
    float acc[N_OUT];
    #pragma unroll
    for (int o = 0; o < N_OUT; ++o) acc[o] = 0.f;

    #pragma unroll
    for (int k = 0; k < NAMPS; ++k) {
        const int x = xD | (k << 1);
        int t = x ^ (x >> 1); t ^= t >> 2; t ^= t >> 4; t ^= t >> 8;
        const int y = (t & 0x0FFF) | (((t ^ (x >> 12)) & 1) << 12);
        const float p = a[k].x * a[k].x + a[k].y * a[k].y;
        #pragma unroll
        for (int o = 0; o < N_OUT; ++o)
            acc[o] += ((y >> (12 - o)) & 1) ? -p : p;
    }

    #pragma unroll
    for (int off = 32; off >= 1; off >>= 1) {
        #pragma unroll
        for (int o = 0; o < N_OUT; ++o) acc[o] += __shfl_down(acc[o], off);
    }
    const int wave = tid >> 6;
    const int lane = tid & 63;
    if (lane == 0) {
        #pragma unroll
        for (int o = 0; o < N_OUT; ++o) red[wave][o] = acc[o];
    }
    __syncthreads();
    if (tid < N_OUT) {
        float s = 0.f;
        #pragma unroll
        for (int w = 0; w < NWAVES; ++w) s += red[w][tid];
        out[b * N_OUT + tid] = s;
    }
}

extern "C" void kernel_launch(void* const* d_in, const int* in_sizes, int n_in,
                              void* d_out, int out_size, void* d_ws, size_t ws_size,
                              hipStream_t stream) {
    const float* inputs  = (const float*)d_in[0];
    const float* weights = (const float*)d_in[1];
    const float* embed   = (const float*)d_in[2];
    float* out = (float*)d_out;
    vqc_kernel<<<BATCH, NTHREADS, 0, stream>>>(inputs, weights, embed, out);
}

// Round 8
// 47.349 us; speedup vs baseline: 1.6583x; 1.0029x over previous
//
#include <hip/hip_runtime.h>
#include <math.h>

#define N_WIRES 13
#define DIM 8192
#define N_LAYERS 3
#define N_OUT 10
#define BATCH 512
#define NTHREADS 1024
#define NAMPS 8
#define NWAVES (NTHREADS / 64)

typedef float v2f __attribute__((ext_vector_type(2)));

// ---- packed complex arithmetic via VOP3P (v_pk_*_f32) ----
// d = u (*) a   [complex mul]
#define CMUL_PK(d, u, a) do { \
    asm("v_pk_mul_f32 %0, %1, %2 op_sel:[0,0] op_sel_hi:[0,1]" \
        : "=v"(d) : "v"(u), "v"(a)); \
    asm("v_pk_fma_f32 %0, %1, %2, %0 op_sel:[1,1,0] op_sel_hi:[1,0,1] neg_lo:[0,1,0]" \
        : "+v"(d) : "v"(u), "v"(a)); \
} while (0)

// d += u (*) a  [complex fma]
#define CFMA_PK(d, u, a) do { \
    asm("v_pk_fma_f32 %0, %1, %2, %0 op_sel:[0,0,0] op_sel_hi:[0,1,1]" \
        : "+v"(d) : "v"(u), "v"(a)); \
    asm("v_pk_fma_f32 %0, %1, %2, %0 op_sel:[1,1,0] op_sel_hi:[1,0,1] neg_lo:[0,1,0]" \
        : "+v"(d) : "v"(u), "v"(a)); \
} while (0)

__device__ __forceinline__ void bfly(v2f& a0, v2f& a1,
                                     v2f u00, v2f u01, v2f u10, v2f u11) {
    v2f n0, n1;
    CMUL_PK(n0, u00, a0); CFMA_PK(n0, u01, a1);
    CMUL_PK(n1, u10, a0); CFMA_PK(n1, u11, a1);
    a0 = n0; a1 = n1;
}

// Gate on a register bit: pairs (k0, k0|MASK) within the 8 per-thread amps.
#define REG_GATE(MASK, W) do { \
    const float4 uA = uu4[l][W][0]; \
    const float4 uB = uu4[l][W][1]; \
    const v2f u00 = {uA.x, uA.y}, u01 = {uA.z, uA.w}; \
    const v2f u10 = {uB.x, uB.y}, u11 = {uB.z, uB.w}; \
    _Pragma("unroll") \
    for (int k0 = 0; k0 < NAMPS; ++k0) { \
        if (k0 & (MASK)) continue; \
        bfly(a[k0], a[k0 | (MASK)], u00, u01, u10, u11); \
    } \
} while (0)

// Gate on lane bit 0 (x bit 0): partner via DPP quad_perm(1,0,3,2) -- VALU pipe.
#define DPP1_GATE(W) do { \
    const float4 uA = uu4[l][W][0]; \
    const float4 uB = uu4[l][W][1]; \
    const bool hb = (tid & 1) != 0; \
    const v2f ua = hb ? (v2f){uB.z, uB.w} : (v2f){uA.x, uA.y}; \
    const v2f up = hb ? (v2f){uB.x, uB.y} : (v2f){uA.z, uA.w}; \
    _Pragma("unroll") \
    for (int k = 0; k < NAMPS; ++k) { \
        v2f p; \
        p.x = __int_as_float(__builtin_amdgcn_update_dpp(0, __float_as_int(a[k].x), 0xB1, 0xF, 0xF, true)); \
        p.y = __int_as_float(__builtin_amdgcn_update_dpp(0, __float_as_int(a[k].y), 0xB1, 0xF, 0xF, true)); \
        v2f n; CMUL_PK(n, ua, a[k]); CFMA_PK(n, up, p); \
        a[k] = n; \
    } \
} while (0)

// CNOT-ring permutation y(x) (GF2-linear) and LDS address swizzle (GF2-linear)
__device__ __forceinline__ constexpr int ymap(int x) {
    int t = x ^ (x >> 1); t ^= t >> 2; t ^= t >> 4; t ^= t >> 8;
    return (t & 0x0FFF) | (((t ^ (x >> 12)) & 1) << 12);
}
__device__ __forceinline__ constexpr int swz(int v) {
    return v ^ (((v >> 5) & 7) << 1);
}

__attribute__((amdgpu_num_vgpr(64)))
__global__ __launch_bounds__(NTHREADS) void vqc_kernel(
    const float* __restrict__ inputs,
    const float* __restrict__ weights,
    const float* __restrict__ embed,
    float* __restrict__ out)
{
    __shared__ v2f  s2[DIM];                        // state, addresses via swz(x)
    __shared__ float4 uu4[N_LAYERS][N_WIRES][2];    // Rot matrices
    __shared__ float  co[N_LAYERS][N_WIRES];
    __shared__ float  ga[N_LAYERS][N_WIRES];
    __shared__ v2f  Ek[N_LAYERS][8];                // exp(-i(S-2C_k)), k = x bits 12..10 (l=0 pre-scaled)
    __shared__ v2f  Eh[N_LAYERS][16];               // exp(+2i*C_h), h = x bits 9..6
    __shared__ v2f  El[N_LAYERS][64];               // exp(+2i*C_lo), lo = x bits 5..0
    __shared__ v2f  G2[N_LAYERS], G6b[N_LAYERS], G12[N_LAYERS];
    __shared__ float red[NWAVES][N_OUT];

    const int b   = blockIdx.x;
    const int tid = threadIdx.x;

    // ---- setup stage 1: co/ga + U matrices + boundary gamma factors ----
    if (tid < N_LAYERS * N_WIRES) {
        const int l = tid / N_WIRES;
        const int w = tid - l * N_WIRES;
        const int base = (l * N_WIRES + w) * 3;
        const float om = embed[base + 0];
        const float bi = embed[base + 1];
        const float gm = embed[base + 2];
        co[l][w] = inputs[b * N_WIRES + w] * om + bi;
        ga[l][w] = gm;

        const float phi = weights[base + 0];
        const float th  = weights[base + 1];
        const float omg = weights[base + 2];
        float c, s, ca, sa, cb, sb;
        __sincosf(0.5f * th, &s, &c);
        __sincosf(0.5f * (phi + omg), &sa, &ca);
        __sincosf(0.5f * (phi - omg), &sb, &cb);
        uu4[l][w][0] = make_float4( ca * c, -sa * c, -cb * s, -sb * s);  // U00,U01
        uu4[l][w][1] = make_float4( cb * s, -sb * s,  ca * c,  sa * c);  // U10,U11

        if (w == 2 || w == 6 || w == 12) {
            float s2v, c2v; __sincosf(2.f * gm, &s2v, &c2v);
            if (w == 2)  G2[l]  = (v2f){c2v, s2v};   // boundary x10^x9
            if (w == 6)  G6b[l] = (v2f){c2v, s2v};   // boundary x6^x5
            if (w == 12) G12[l] = (v2f){c2v, s2v};   // wrap x0^x12
        }
    }
    __syncthreads();

    // ---- setup stage 2: phase tables ----
    if (tid < N_LAYERS * 8) {                       // Ek: k = x12..10 (wires 0-2), folds S + norm
        const int l = tid >> 3, k = tid & 7;
        float S = 0.f;
        #pragma unroll
        for (int w = 0; w < N_WIRES; ++w) S += co[l][w] + ga[l][w];
        const int b2 = (k >> 2) & 1, b1 = (k >> 1) & 1, b0 = k & 1;
        float v = S;
        if (b2) v -= 2.f * co[l][0];
        if (b1) v -= 2.f * co[l][1];
        if (b0) v -= 2.f * co[l][2];
        if (b2 ^ b1) v -= 2.f * ga[l][0];
        if (b1 ^ b0) v -= 2.f * ga[l][1];
        float sv, cv; __sincosf(v, &sv, &cv);
        const float sc = (l == 0) ? 0.011048543456039806f : 1.f;   // 8192^-0.5
        Ek[l][k] = (v2f){sc * cv, -sc * sv};
    }
    if (tid >= 64 && tid < 64 + N_LAYERS * 16) {    // Eh: h = x9..6 (wires 3-6)
        const int t = tid - 64, l = t >> 4, h = t & 15;
        const int h3 = (h >> 3) & 1, h2 = (h >> 2) & 1, h1 = (h >> 1) & 1, h0 = h & 1;
        float T = 0.f;
        if (h3) T += co[l][3];
        if (h2) T += co[l][4];
        if (h1) T += co[l][5];
        if (h0) T += co[l][6];
        if (h3 ^ h2) T += ga[l][3];
        if (h2 ^ h1) T += ga[l][4];
        if (h1 ^ h0) T += ga[l][5];
        float sv, cv; __sincosf(2.f * T, &sv, &cv);
        Eh[l][h] = (v2f){cv, sv};
    }
    if (tid >= 128 && tid < 128 + N_LAYERS * 64) {  // El: m = x5..0 (wires 7-12)
        const int t = tid - 128, l = t >> 6, m = t & 63;
        const int b5 = (m >> 5) & 1, b4 = (m >> 4) & 1, b3 = (m >> 3) & 1;
        const int b2 = (m >> 2) & 1, b1 = (m >> 1) & 1, b0 = m & 1;
        float T = 0.f;
        if (b5) T += co[l][7];
        if (b4) T += co[l][8];
        if (b3) T += co[l][9];
        if (b2) T += co[l][10];
        if (b1) T += co[l][11];
        if (b0) T += co[l][12];
        if (b5 ^ b4) T += ga[l][7];
        if (b4 ^ b3) T += ga[l][8];
        if (b3 ^ b2) T += ga[l][9];
        if (b2 ^ b1) T += ga[l][10];
        if (b1 ^ b0) T += ga[l][11];
        float sv, cv; __sincosf(2.f * T, &sv, &cv);
        El[l][m] = (v2f){cv, sv};
    }
    __syncthreads();

    // thread-constant addressing; address of x is swz(x), folded per pass
    const int tA = tid ^ (((tid >> 5) & 7) << 1);                         // A: addr = (k<<10)|tA
    const int bB = (((tid >> 7) << 10) | (tid & 127))
                 ^ ((((tid >> 6) & 1) << 2) | (((tid >> 5) & 1) << 1));   // B: ^ (k<<7) ^ ((k&1)<<3)
    const int bC = (((tid >> 4) << 7) | (tid & 15))
                 ^ (((tid >> 4) & 1) << 3);                               // C: ^ (k<<4) ^ (k&6)
    const int xD = ((tid >> 1) << 4) | (tid & 1);                         // D: true x base
    const int bD = swz(xD);                                               // D: addr = ^ (k<<1)
    const int yD  = ymap(xD);                                             // permuted base index
    const int syD = swz(yD);                                              // scatter addr base

    v2f a[NAMPS];

    #pragma unroll 1
    for (int l = 0; l < N_LAYERS; ++l) {
        // ===== Pass A: x = (k<<10)|tid; phase + wires 0-2 =====
        {
            const bool t9 = ((tid >> 9) & 1) != 0;
            const bool t0 = (tid & 1) != 0;
            const bool c6 = (((tid >> 6) ^ (tid >> 5)) & 1) != 0;
            v2f ep; CMUL_PK(ep, Eh[l][(tid >> 6) & 15], El[l][tid & 63]);
            { v2f tb; CMUL_PK(tb, ep, G6b[l]); ep = c6 ? tb : ep; }
            v2f eg2; CMUL_PK(eg2, ep, G2[l]);
            const v2f Fe = t9 ? eg2 : ep,  Fo = t9 ? ep : eg2;   // by k bit0 (x10)
            const v2f one = {1.f, 0.f};
            const v2f Ge = t0 ? G12[l] : one, Go = t0 ? one : G12[l]; // by k bit2 (x12)

            if (l == 0) {
                #pragma unroll
                for (int k = 0; k < NAMPS; ++k) {
                    v2f f; CMUL_PK(f, Ek[l][k], (k & 1) ? Fo : Fe);
                    CMUL_PK(a[k], f, (k & 4) ? Go : Ge);
                }
            } else {
                #pragma unroll
                for (int k = 0; k < NAMPS; ++k) {
                    v2f f; CMUL_PK(f, Ek[l][k], (k & 1) ? Fo : Fe);
                    v2f g; CMUL_PK(g, f, (k & 4) ? Go : Ge);
                    const v2f v = s2[(k << 10) | tA];
                    CMUL_PK(a[k], v, g);
                }
            }
        }

        REG_GATE(4, 0);   // wire 0 <-> x12 <-> k bit 2
        REG_GATE(2, 1);
        REG_GATE(1, 2);
        #pragma unroll
        for (int k = 0; k < NAMPS; ++k)
            s2[(k << 10) | tA] = a[k];
        __syncthreads();

        // ===== Pass B: k = x9..7; wires 3-5 =====
        #pragma unroll
        for (int k = 0; k < NAMPS; ++k)
            a[k] = s2[bB ^ (k << 7) ^ ((k & 1) << 3)];
        REG_GATE(4, 3);
        REG_GATE(2, 4);
        REG_GATE(1, 5);
        #pragma unroll
        for (int k = 0; k < NAMPS; ++k)
            s2[bB ^ (k << 7) ^ ((k & 1) << 3)] = a[k];
        __syncthreads();

        // ===== Pass C: k = x6..4; wires 6-8 =====
        #pragma unroll
        for (int k = 0; k < NAMPS; ++k)
            a[k] = s2[bC ^ (k << 4) ^ (k & 6)];
        REG_GATE(4, 6);
        REG_GATE(2, 7);
        REG_GATE(1, 8);
        #pragma unroll
        for (int k = 0; k < NAMPS; ++k)
            s2[bC ^ (k << 4) ^ (k & 6)] = a[k];
        __syncthreads();

        // ===== Pass D: k = x3..1; wires 9-11 + wire 12 (lane bit 0) =====
        #pragma unroll
        for (int k = 0; k < NAMPS; ++k)
            a[k] = s2[bD ^ (k << 1)];
        if (l < N_LAYERS - 1) __syncthreads();   // all loads done before scatter

        REG_GATE(4, 9);
        REG_GATE(2, 10);
        REG_GATE(1, 11);
        DPP1_GATE(12);

        if (l < N_LAYERS - 1) {
            // fused CNOT-ring permutation: scatter amp(x) to swz(y(x)) = syD ^ const
            #pragma unroll
            for (int k = 0; k < NAMPS; ++k)
                s2[syD ^ swz(ymap(k << 1))] = a[k];
            __syncthreads();
        }
    }

    // ---- fused readout: y = yD ^ ymap(k<<1); k-part signs fold at compile time ----
    float p[NAMPS];
    #pragma unroll
    for (int k = 0; k < NAMPS; ++k)
        p[k] = a[k].x * a[k].x + a[k].y * a[k].y;

    float acc[N_OUT];
    #pragma unroll
    for (int o = 0; o < N_OUT; ++o) {
        const int bp = 12 - o;
        float s = 0.f;
        #pragma unroll
        for (int k = 0; k < NAMPS; ++k) {
            const int yk = ymap(k << 1);
            s += ((yk >> bp) & 1) ? -p[k] : p[k];   // compile-time sign
        }
        acc[o] = ((yD >> bp) & 1) ? -s : s;          // runtime sign (1 cndmask)
    }

    #pragma unroll
    for (int off = 32; off >= 1; off >>= 1) {
        #pragma unroll
        for (int o = 0; o < N_OUT; ++o) acc[o] += __shfl_down(acc[o], off);
    }
    const int wave = tid >> 6;
    const int lane = tid & 63;
    if (lane == 0) {
        #pragma unroll
        for (int o = 0; o < N_OUT; ++o) red[wave][o] = acc[o];
    }
    __syncthreads();
    if (tid < N_OUT) {
        float s = 0.f;
        #pragma unroll
        for (int w = 0; w < NWAVES; ++w) s += red[w][tid];
        out[b * N_OUT + tid] = s;
    }
}

extern "C" void kernel_launch(void* const* d_in, const int* in_sizes, int n_in,
                              void* d_out, int out_size, void* d_ws, size_t ws_size,
                              hipStream_t stream) {
    const float* inputs  = (const float*)d_in[0];
    const float* weights = (const float*)d_in[1];
    const float* embed   = (const float*)d_in[2];
    float* out = (float*)d_out;
    vqc_kernel<<<BATCH, NTHREADS, 0, stream>>>(inputs, weights, embed, out);
}

// Round 10
// 45.482 us; speedup vs baseline: 1.7263x; 1.0411x over previous
//
#include <hip/hip_runtime.h>
#include <math.h>

#define N_WIRES 13
#define DIM 8192
#define N_LAYERS 3
#define N_OUT 10
#define BATCH 512
#define NTHREADS 1024
#define NAMPS 8
#define NWAVES (NTHREADS / 64)

typedef float v2f __attribute__((ext_vector_type(2)));
typedef __fp16 v2h __attribute__((ext_vector_type(2)));

// ---- packed complex arithmetic via VOP3P (v_pk_*_f32) ----
// d = u (*) a   [complex mul]
#define CMUL_PK(d, u, a) do { \
    asm("v_pk_mul_f32 %0, %1, %2 op_sel:[0,0] op_sel_hi:[0,1]" \
        : "=v"(d) : "v"(u), "v"(a)); \
    asm("v_pk_fma_f32 %0, %1, %2, %0 op_sel:[1,1,0] op_sel_hi:[1,0,1] neg_lo:[0,1,0]" \
        : "+v"(d) : "v"(u), "v"(a)); \
} while (0)

// d += u (*) a  [complex fma]
#define CFMA_PK(d, u, a) do { \
    asm("v_pk_fma_f32 %0, %1, %2, %0 op_sel:[0,0,0] op_sel_hi:[0,1,1]" \
        : "+v"(d) : "v"(u), "v"(a)); \
    asm("v_pk_fma_f32 %0, %1, %2, %0 op_sel:[1,1,0] op_sel_hi:[1,0,1] neg_lo:[0,1,0]" \
        : "+v"(d) : "v"(u), "v"(a)); \
} while (0)

__device__ __forceinline__ void bfly(v2f& a0, v2f& a1,
                                     v2f u00, v2f u01, v2f u10, v2f u11) {
    v2f n0, n1;
    CMUL_PK(n0, u00, a0); CFMA_PK(n0, u01, a1);
    CMUL_PK(n1, u10, a0); CFMA_PK(n1, u11, a1);
    a0 = n0; a1 = n1;
}

// Gate on a register bit: pairs (k0, k0|MASK) within the 8 per-thread amps.
#define REG_GATE(MASK, W) do { \
    const float4 uA = uu4[l][W][0]; \
    const float4 uB = uu4[l][W][1]; \
    const v2f u00 = {uA.x, uA.y}, u01 = {uA.z, uA.w}; \
    const v2f u10 = {uB.x, uB.y}, u11 = {uB.z, uB.w}; \
    _Pragma("unroll") \
    for (int k0 = 0; k0 < NAMPS; ++k0) { \
        if (k0 & (MASK)) continue; \
        bfly(a[k0], a[k0 | (MASK)], u00, u01, u10, u11); \
    } \
} while (0)

// Gate on lane bit 0 (x bit 0): partner via DPP quad_perm(1,0,3,2) -- VALU pipe.
#define DPP1_GATE(W) do { \
    const float4 uA = uu4[l][W][0]; \
    const float4 uB = uu4[l][W][1]; \
    const bool hb = (tid & 1) != 0; \
    const v2f ua = hb ? (v2f){uB.z, uB.w} : (v2f){uA.x, uA.y}; \
    const v2f up = hb ? (v2f){uB.x, uB.y} : (v2f){uA.z, uA.w}; \
    _Pragma("unroll") \
    for (int k = 0; k < NAMPS; ++k) { \
        v2f p; \
        p.x = __int_as_float(__builtin_amdgcn_update_dpp(0, __float_as_int(a[k].x), 0xB1, 0xF, 0xF, true)); \
        p.y = __int_as_float(__builtin_amdgcn_update_dpp(0, __float_as_int(a[k].y), 0xB1, 0xF, 0xF, true)); \
        v2f n; CMUL_PK(n, ua, a[k]); CFMA_PK(n, up, p); \
        a[k] = n; \
    } \
} while (0)

// CNOT-ring permutation y(x) (GF2-linear) and LDS address swizzle (GF2-linear,
// derived for 4-byte elements: banks = addr&31; every pass pattern <=2 lanes/bank)
__device__ __forceinline__ constexpr int ymap(int x) {
    int t = x ^ (x >> 1); t ^= t >> 2; t ^= t >> 4; t ^= t >> 8;
    return (t & 0x0FFF) | (((t ^ (x >> 12)) & 1) << 12);
}
__device__ __forceinline__ constexpr int swz(int v) {
    return v ^ (((v >> 5) & 0xF) << 1);
}

__device__ __forceinline__ v2f h2f(v2h h) {
    return (v2f){(float)h.x, (float)h.y};
}

__attribute__((amdgpu_num_vgpr(64)))
__global__ __launch_bounds__(NTHREADS) void vqc_kernel(
    const float* __restrict__ inputs,
    const float* __restrict__ weights,
    const float* __restrict__ embed,
    float* __restrict__ out)
{
    __shared__ v2h  s2[DIM];                        // state (fp16 pairs), addr = swz(x)
    __shared__ float4 uu4[N_LAYERS][N_WIRES][2];    // Rot matrices
    __shared__ float  co[N_LAYERS][N_WIRES];
    __shared__ float  ga[N_LAYERS][N_WIRES];
    __shared__ v2f  Ek[N_LAYERS][8];                // exp(-i(S-2C_k)), k = x bits 12..10 (l=0 pre-scaled)
    __shared__ v2f  Eh[N_LAYERS][16];               // exp(+2i*C_h), h = x bits 9..6
    __shared__ v2f  El[N_LAYERS][64];               // exp(+2i*C_lo), lo = x bits 5..0
    __shared__ v2f  G2[N_LAYERS], G6b[N_LAYERS], G12[N_LAYERS];
    __shared__ float red[NWAVES][N_OUT];

    const int b   = blockIdx.x;
    const int tid = threadIdx.x;

    // ---- setup stage 1: co/ga + U matrices + boundary gamma factors ----
    if (tid < N_LAYERS * N_WIRES) {
        const int l = tid / N_WIRES;
        const int w = tid - l * N_WIRES;
        const int base = (l * N_WIRES + w) * 3;
        const float om = embed[base + 0];
        const float bi = embed[base + 1];
        const float gm = embed[base + 2];
        co[l][w] = inputs[b * N_WIRES + w] * om + bi;
        ga[l][w] = gm;

        const float phi = weights[base + 0];
        const float th  = weights[base + 1];
        const float omg = weights[base + 2];
        float c, s, ca, sa, cb, sb;
        __sincosf(0.5f * th, &s, &c);
        __sincosf(0.5f * (phi + omg), &sa, &ca);
        __sincosf(0.5f * (phi - omg), &sb, &cb);
        uu4[l][w][0] = make_float4( ca * c, -sa * c, -cb * s, -sb * s);  // U00,U01
        uu4[l][w][1] = make_float4( cb * s, -sb * s,  ca * c,  sa * c);  // U10,U11

        if (w == 2 || w == 6 || w == 12) {
            float s2v, c2v; __sincosf(2.f * gm, &s2v, &c2v);
            if (w == 2)  G2[l]  = (v2f){c2v, s2v};   // boundary x10^x9
            if (w == 6)  G6b[l] = (v2f){c2v, s2v};   // boundary x6^x5
            if (w == 12) G12[l] = (v2f){c2v, s2v};   // wrap x0^x12
        }
    }
    __syncthreads();

    // ---- setup stage 2: phase tables ----
    if (tid < N_LAYERS * 8) {                       // Ek: k = x12..10 (wires 0-2), folds S + norm
        const int l = tid >> 3, k = tid & 7;
        float S = 0.f;
        #pragma unroll
        for (int w = 0; w < N_WIRES; ++w) S += co[l][w] + ga[l][w];
        const int b2 = (k >> 2) & 1, b1 = (k >> 1) & 1, b0 = k & 1;
        float v = S;
        if (b2) v -= 2.f * co[l][0];
        if (b1) v -= 2.f * co[l][1];
        if (b0) v -= 2.f * co[l][2];
        if (b2 ^ b1) v -= 2.f * ga[l][0];
        if (b1 ^ b0) v -= 2.f * ga[l][1];
        float sv, cv; __sincosf(v, &sv, &cv);
        const float sc = (l == 0) ? 0.011048543456039806f : 1.f;   // 8192^-0.5
        Ek[l][k] = (v2f){sc * cv, -sc * sv};
    }
    if (tid >= 64 && tid < 64 + N_LAYERS * 16) {    // Eh: h = x9..6 (wires 3-6)
        const int t = tid - 64, l = t >> 4, h = t & 15;
        const int h3 = (h >> 3) & 1, h2 = (h >> 2) & 1, h1 = (h >> 1) & 1, h0 = h & 1;
        float T = 0.f;
        if (h3) T += co[l][3];
        if (h2) T += co[l][4];
        if (h1) T += co[l][5];
        if (h0) T += co[l][6];
        if (h3 ^ h2) T += ga[l][3];
        if (h2 ^ h1) T += ga[l][4];
        if (h1 ^ h0) T += ga[l][5];
        float sv, cv; __sincosf(2.f * T, &sv, &cv);
        Eh[l][h] = (v2f){cv, sv};
    }
    if (tid >= 128 && tid < 128 + N_LAYERS * 64) {  // El: m = x5..0 (wires 7-12)
        const int t = tid - 128, l = t >> 6, m = t & 63;
        const int b5 = (m >> 5) & 1, b4 = (m >> 4) & 1, b3 = (m >> 3) & 1;
        const int b2 = (m >> 2) & 1, b1 = (m >> 1) & 1, b0 = m & 1;
        float T = 0.f;
        if (b5) T += co[l][7];
        if (b4) T += co[l][8];
        if (b3) T += co[l][9];
        if (b2) T += co[l][10];
        if (b1) T += co[l][11];
        if (b0) T += co[l][12];
        if (b5 ^ b4) T += ga[l][7];
        if (b4 ^ b3) T += ga[l][8];
        if (b3 ^ b2) T += ga[l][9];
        if (b2 ^ b1) T += ga[l][10];
        if (b1 ^ b0) T += ga[l][11];
        float sv, cv; __sincosf(2.f * T, &sv, &cv);
        El[l][m] = (v2f){cv, sv};
    }
    __syncthreads();

    // thread-constant addressing; address of x is swz(x), XOR-folded per pass
    const int tA = tid ^ (((tid >> 5) & 0xF) << 1);                       // A: addr = (k<<10)|tA
    const int bB = (((tid >> 7) << 10) | (tid & 127))
                 ^ ((((tid >> 5) & 1) << 1) | (((tid >> 6) & 1) << 2));   // B: ^ (k<<7) ^ ((k&3)<<3)
    const int bC = (((tid >> 4) << 7) | (tid & 15))
                 ^ ((((tid >> 4) & 1) << 3) | (((tid >> 5) & 1) << 4));   // C: ^ (k<<4) ^ ((k>>1)<<1)
    const int xD = ((tid >> 1) << 4) | (tid & 1);                         // D: true x base
    const int bD = xD ^ (((tid >> 2) & 0xF) << 1);                        // D: addr = ^ (k<<1)
    const int yD  = ymap(xD);                                             // permuted base index
    const int syD = swz(yD);                                              // scatter addr base

    v2f a[NAMPS];

    #pragma unroll 1
    for (int l = 0; l < N_LAYERS; ++l) {
        // ===== Pass A: x = (k<<10)|tid; phase + wires 0-2 =====
        {
            const bool t9 = ((tid >> 9) & 1) != 0;
            const bool t0 = (tid & 1) != 0;
            const bool c6 = (((tid >> 6) ^ (tid >> 5)) & 1) != 0;
            v2f ep; CMUL_PK(ep, Eh[l][(tid >> 6) & 15], El[l][tid & 63]);
            { v2f tb; CMUL_PK(tb, ep, G6b[l]); ep = c6 ? tb : ep; }
            v2f eg2; CMUL_PK(eg2, ep, G2[l]);
            const v2f Fe = t9 ? eg2 : ep,  Fo = t9 ? ep : eg2;   // by k bit0 (x10)
            const v2f one = {1.f, 0.f};
            const v2f Ge = t0 ? G12[l] : one, Go = t0 ? one : G12[l]; // by k bit2 (x12)

            if (l == 0) {
                #pragma unroll
                for (int k = 0; k < NAMPS; ++k) {
                    v2f f; CMUL_PK(f, Ek[l][k], (k & 1) ? Fo : Fe);
                    CMUL_PK(a[k], f, (k & 4) ? Go : Ge);
                }
            } else {
                #pragma unroll
                for (int k = 0; k < NAMPS; ++k) {
                    v2f f; CMUL_PK(f, Ek[l][k], (k & 1) ? Fo : Fe);
                    v2f g; CMUL_PK(g, f, (k & 4) ? Go : Ge);
                    const v2f v = h2f(s2[(k << 10) | tA]);
                    CMUL_PK(a[k], v, g);
                }
            }
        }

        REG_GATE(4, 0);   // wire 0 <-> x12 <-> k bit 2
        REG_GATE(2, 1);
        REG_GATE(1, 2);
        #pragma unroll
        for (int k = 0; k < NAMPS; ++k)
            s2[(k << 10) | tA] = __builtin_amdgcn_cvt_pkrtz(a[k].x, a[k].y);
        __syncthreads();

        // ===== Pass B: k = x9..7; wires 3-5 =====
        #pragma unroll
        for (int k = 0; k < NAMPS; ++k)
            a[k] = h2f(s2[bB ^ (k << 7) ^ ((k & 3) << 3)]);
        REG_GATE(4, 3);
        REG_GATE(2, 4);
        REG_GATE(1, 5);
        #pragma unroll
        for (int k = 0; k < NAMPS; ++k)
            s2[bB ^ (k << 7) ^ ((k & 3) << 3)] = __builtin_amdgcn_cvt_pkrtz(a[k].x, a[k].y);
        __syncthreads();

        // ===== Pass C: k = x6..4; wires 6-8 =====
        #pragma unroll
        for (int k = 0; k < NAMPS; ++k)
            a[k] = h2f(s2[bC ^ (k << 4) ^ ((k >> 1) << 1)]);
        REG_GATE(4, 6);
        REG_GATE(2, 7);
        REG_GATE(1, 8);
        #pragma unroll
        for (int k = 0; k < NAMPS; ++k)
            s2[bC ^ (k << 4) ^ ((k >> 1) << 1)] = __builtin_amdgcn_cvt_pkrtz(a[k].x, a[k].y);
        __syncthreads();

        // ===== Pass D: k = x3..1; wires 9-11 + wire 12 (lane bit 0) =====
        #pragma unroll
        for (int k = 0; k < NAMPS; ++k)
            a[k] = h2f(s2[bD ^ (k << 1)]);
        if (l < N_LAYERS - 1) __syncthreads();   // all loads done before scatter

        REG_GATE(4, 9);
        REG_GATE(2, 10);
        REG_GATE(1, 11);
        DPP1_GATE(12);

        if (l < N_LAYERS - 1) {
            // fused CNOT-ring permutation: scatter amp(x) to swz(y(x)) = syD ^ const
            #pragma unroll
            for (int k = 0; k < NAMPS; ++k)
                s2[syD ^ swz(ymap(k << 1))] = __builtin_amdgcn_cvt_pkrtz(a[k].x, a[k].y);
            __syncthreads();
        }
    }

    // ---- fused readout: y = yD ^ ymap(k<<1); k-part signs fold at compile time ----
    float p[NAMPS];
    #pragma unroll
    for (int k = 0; k < NAMPS; ++k)
        p[k] = a[k].x * a[k].x + a[k].y * a[k].y;

    float acc[N_OUT];
    #pragma unroll
    for (int o = 0; o < N_OUT; ++o) {
        const int bp = 12 - o;
        float s = 0.f;
        #pragma unroll
        for (int k = 0; k < NAMPS; ++k) {
            const int yk = ymap(k << 1);
            s += ((yk >> bp) & 1) ? -p[k] : p[k];   // compile-time sign
        }
        acc[o] = ((yD >> bp) & 1) ? -s : s;          // runtime sign (1 cndmask)
    }

    #pragma unroll
    for (int off = 32; off >= 1; off >>= 1) {
        #pragma unroll
        for (int o = 0; o < N_OUT; ++o) acc[o] += __shfl_down(acc[o], off);
    }
    const int wave = tid >> 6;
    const int lane = tid & 63;
    if (lane == 0) {
        #pragma unroll
        for (int o = 0; o < N_OUT; ++o) red[wave][o] = acc[o];
    }
    __syncthreads();
    if (tid < N_OUT) {
        float s = 0.f;
        #pragma unroll
        for (int w = 0; w < NWAVES; ++w) s += red[w][tid];
        out[b * N_OUT + tid] = s;
    }
}

extern "C" void kernel_launch(void* const* d_in, const int* in_sizes, int n_in,
                              void* d_out, int out_size, void* d_ws, size_t ws_size,
                              hipStream_t stream) {
    const float* inputs  = (const float*)d_in[0];
    const float* weights = (const float*)d_in[1];
    const float* embed   = (const float*)d_in[2];
    float* out = (float*)d_out;
    vqc_kernel<<<BATCH, NTHREADS, 0, stream>>>(inputs, weights, embed, out);
}